// Round 14
// baseline (194.973 us; speedup 1.0000x reference)
//
#include <hip/hip_runtime.h>
#include <math.h>
#include <stdint.h>

#define N_NODES 50000
#define N_EDGES 800000
#define IN_DIM  512
#define OUT_DIM 256
#define NBLK_SCAN 49   // ceil(50000/1024)

typedef __attribute__((ext_vector_type(8))) short short8;
typedef __attribute__((ext_vector_type(4))) float f32x4;

__device__ inline unsigned f2bf(float x) {
  unsigned u = __float_as_uint(x);
  return (u + 0x7FFFu + ((u >> 16) & 1u)) >> 16;   // RNE
}
__device__ inline float bf2f(unsigned short h) {
  return __uint_as_float(((unsigned)h) << 16);
}

// ---------------- K1: fused wconv (blocks 0..511) + deg_count (rest) --------
// Wtp[((nt*16+kk)*64 + lane)*8 + j] = bf16(W[k][c]), k=kk*32+(lane>>4)*8+j,
// c = nt*16 + (lane&15).
#define WCONV_BLKS 512
__global__ __launch_bounds__(256) void wconv_deg(const float* __restrict__ W,
                                                 unsigned short* __restrict__ Wtp,
                                                 const int* __restrict__ dst,
                                                 int* __restrict__ deg) {
  if (blockIdx.x < WCONV_BLKS) {
    int i = blockIdx.x * 256 + threadIdx.x;   // over 131072
    int c = i & 255, k = i >> 8;
    int nt = c >> 4, kk = k >> 5;
    int lane = (((k & 31) >> 3) << 4) | (c & 15);
    int j = k & 7;
    Wtp[(((size_t)(nt * 16 + kk)) * 64 + lane) * 8 + j] =
        (unsigned short)f2bf(W[(size_t)k * OUT_DIM + c]);
  } else {
    int e = (blockIdx.x - WCONV_BLKS) * 256 + threadIdx.x;
    if (e < N_EDGES) atomicAdd(&deg[dst[e]], 1);
  }
}

// ---------------- K2: ft = bf16(feat @ W + b), 2-tile pipelined -------------
// block: 512 thr = 8 waves; 64 rows/block as 2 tiles of 32; single 32 KB LDS.
// Pipeline: LOAD(t0) WRITE(t0) bar | LOAD(t1) COMPUTE(t0) bar WRITE(t1) bar
// COMPUTE(t1)  -> tile-1 HBM latency hides under tile-0 compute (T14).
// Lane roles (per tile): l15=lane&15, row rt=wv*4+(lane>>4), chunks l15+16j.
// LDS byte = ((mg*16+kk)*64 + slot)*16 + h*8; kk=2j+b3;
//   slot = (kgrp*16+row16) ^ (kk&7) ^ ((row16&3)<<1).
#define TROWS 32
#define BROWS 64
__global__ __launch_bounds__(512, 4) void gemm_mfma(const float* __restrict__ feat,
                        const unsigned short* __restrict__ Wtp,
                        const float* __restrict__ bias,
                        const float* __restrict__ Wl, const float* __restrict__ bl,
                        const float* __restrict__ Wr, const float* __restrict__ br,
                        unsigned short* __restrict__ ftb,
                        float* __restrict__ el, float* __restrict__ er) {
  __shared__ unsigned short Bs[16384];        // 32 KB
  const int tid  = threadIdx.x;
  const int lane = tid & 63;
  const int wv   = tid >> 6;
  const int m0   = blockIdx.x * BROWS;

  const int l15   = lane & 15;
  const int rt    = wv * 4 + (lane >> 4);     // row in tile, 0..31
  const int row16 = rt & 15;
  const int mg    = rt >> 4;
  const int kgrp  = (l15 >> 1) & 3;
  const int b3    = l15 >> 3;
  const int h     = lane & 1;
  const int nt0   = wv * 2;
  const float4* wl4 = (const float4*)Wl;
  const float4* wr4 = (const float4*)Wr;

  float4 f[8];

#define LOADF(tbase)                                                        \
  do {                                                                      \
    int grow = m0 + (tbase) + rt;                                           \
    int gc = grow < N_NODES ? grow : N_NODES - 1;                           \
    const float4* frow = (const float4*)(feat + (size_t)gc * IN_DIM);       \
    _Pragma("unroll")                                                       \
    for (int j = 0; j < 8; ++j) f[j] = frow[l15 + 16 * j];                  \
  } while (0)

#define WRITEF(tbase)                                                       \
  do {                                                                      \
    float elp = 0.f, erp = 0.f;                                             \
    _Pragma("unroll")                                                       \
    for (int j = 0; j < 8; ++j) {                                           \
      float4 wl = wl4[l15 + 16 * j];                                        \
      float4 wr = wr4[l15 + 16 * j];                                        \
      elp += f[j].x * wl.x + f[j].y * wl.y + f[j].z * wl.z + f[j].w * wl.w; \
      erp += f[j].x * wr.x + f[j].y * wr.y + f[j].z * wr.z + f[j].w * wr.w; \
      uint2 pv;                                                             \
      pv.x = f2bf(f[j].x) | (f2bf(f[j].y) << 16);                           \
      pv.y = f2bf(f[j].z) | (f2bf(f[j].w) << 16);                           \
      int kk   = 2 * j + b3;                                                \
      int slot = (kgrp * 16 + row16) ^ (kk & 7) ^ ((row16 & 3) << 1);       \
      *(uint2*)((char*)Bs + (((mg * 16 + kk) * 64) + slot) * 16 + h * 8) = pv; \
    }                                                                       \
    _Pragma("unroll")                                                       \
    for (int o = 1; o < 16; o <<= 1) {                                      \
      elp += __shfl_xor(elp, o);                                            \
      erp += __shfl_xor(erp, o);                                            \
    }                                                                       \
    int grow = m0 + (tbase) + rt;                                           \
    if (l15 == 0 && grow < N_NODES) {                                       \
      el[grow] = elp + bl[0];                                               \
      er[grow] = erp + br[0];                                               \
    }                                                                       \
  } while (0)

#define COMPUTE_STORE(tbase)                                                \
  do {                                                                      \
    f32x4 acc[2][2];                                                        \
    acc[0][0] = (f32x4)0.f; acc[0][1] = (f32x4)0.f;                         \
    acc[1][0] = (f32x4)0.f; acc[1][1] = (f32x4)0.f;                         \
    const unsigned short* wp0 = Wtp + (((size_t)(nt0 + 0) * 16) * 64 + lane) * 8; \
    const unsigned short* wp1 = Wtp + (((size_t)(nt0 + 1) * 16) * 64 + lane) * 8; \
    short8 w0 = *(const short8*)wp0;                                        \
    short8 w1 = *(const short8*)wp1;                                        \
    _Pragma("unroll")                                                       \
    for (int kk = 0; kk < 16; ++kk) {                                       \
      short8 nw0, nw1;                                                      \
      if (kk < 15) {                                                        \
        nw0 = *(const short8*)(wp0 + (size_t)(kk + 1) * 512);               \
        nw1 = *(const short8*)(wp1 + (size_t)(kk + 1) * 512);               \
      }                                                                     \
      int slotr = lane ^ (kk & 7) ^ ((lane & 3) << 1);                      \
      short8 fa0 = *(const short8*)((char*)Bs + (((0 * 16 + kk) * 64) + slotr) * 16); \
      short8 fa1 = *(const short8*)((char*)Bs + (((1 * 16 + kk) * 64) + slotr) * 16); \
      acc[0][0] = __builtin_amdgcn_mfma_f32_16x16x32_bf16(w0, fa0, acc[0][0], 0, 0, 0); \
      acc[0][1] = __builtin_amdgcn_mfma_f32_16x16x32_bf16(w1, fa0, acc[0][1], 0, 0, 0); \
      acc[1][0] = __builtin_amdgcn_mfma_f32_16x16x32_bf16(w0, fa1, acc[1][0], 0, 0, 0); \
      acc[1][1] = __builtin_amdgcn_mfma_f32_16x16x32_bf16(w1, fa1, acc[1][1], 0, 0, 0); \
      w0 = nw0; w1 = nw1;                                                   \
    }                                                                       \
    _Pragma("unroll")                                                       \
    for (int mgi = 0; mgi < 2; ++mgi) {                                     \
      int row = m0 + (tbase) + mgi * 16 + l15;                              \
      if (row < N_NODES) {                                                  \
        unsigned short* orow = ftb + (size_t)row * OUT_DIM;                 \
        _Pragma("unroll")                                                   \
        for (int t = 0; t < 2; ++t) {                                       \
          int col = (nt0 + t) * 16 + (lane >> 4) * 4;                       \
          float4 bb = *(const float4*)(bias + col);                         \
          f32x4 v = acc[mgi][t];                                            \
          uint2 pv;                                                         \
          pv.x = f2bf(v[0] + bb.x) | (f2bf(v[1] + bb.y) << 16);             \
          pv.y = f2bf(v[2] + bb.z) | (f2bf(v[3] + bb.w) << 16);             \
          *(uint2*)(orow + col) = pv;                                       \
        }                                                                   \
      }                                                                     \
    }                                                                       \
  } while (0)

  LOADF(0);
  WRITEF(0);
  __syncthreads();
  LOADF(TROWS);          // tile-1 loads in flight during tile-0 compute
  COMPUTE_STORE(0);
  __syncthreads();       // all waves done reading Bs
  WRITEF(TROWS);
  __syncthreads();
  COMPUTE_STORE(TROWS);

#undef LOADF
#undef WRITEF
#undef COMPUTE_STORE
}

// ---------------- K4: parallel exclusive scan (local + bsums) ---------------
__global__ __launch_bounds__(1024) void scan_local(const int* __restrict__ deg,
                                                   int* __restrict__ off,
                                                   int* __restrict__ bsum) {
  __shared__ int wsum[16];
  int b = blockIdx.x, t = threadIdx.x, i = b * 1024 + t;
  int lane = t & 63, wid = t >> 6;
  int v0 = (i < N_NODES) ? deg[i] : 0;
  int v = v0;
  #pragma unroll
  for (int d = 1; d < 64; d <<= 1) {
    int x = __shfl_up(v, d);
    if (lane >= d) v += x;
  }
  if (lane == 63) wsum[wid] = v;
  __syncthreads();
  if (wid == 0) {
    int wv = (lane < 16) ? wsum[lane] : 0;
    int wo = wv;
    #pragma unroll
    for (int d = 1; d < 16; d <<= 1) {
      int x = __shfl_up(wv, d);
      if (lane >= d) wv += x;
    }
    if (lane < 16) wsum[lane] = wv - wo;
    if (lane == 15) bsum[b] = wv;
  }
  __syncthreads();
  if (i < N_NODES) off[i] = (v - v0) + wsum[wid];   // block-LOCAL exclusive
}

__global__ void scan_bsums(const int* __restrict__ bsum, int* __restrict__ bscan) {
  int t = threadIdx.x;                      // 64 threads, 1 block
  int v = (t < NBLK_SCAN) ? bsum[t] : 0;
  int orig = v;
  for (int d = 1; d < 64; d <<= 1) {
    int x = __shfl_up(v, d);
    if (t >= d) v += x;
  }
  if (t < NBLK_SCAN) bscan[t] = v - orig;   // exclusive block offsets
}

// ---------------- K5: scatter edges into CSR (global = local + bscan) -------
__global__ void scatter_edges(const int* __restrict__ src, const int* __restrict__ dst,
                              const float* __restrict__ el, const float* __restrict__ er,
                              const int* __restrict__ off, const int* __restrict__ bscan,
                              int* __restrict__ cnt, int2* __restrict__ sed) {
  int e = blockIdx.x * blockDim.x + threadIdx.x;
  if (e >= N_EDGES) return;
  int s = src[e], d = dst[e];
  int pos = off[d] + bscan[d >> 10] + atomicAdd(&cnt[d], 1);
  float ev = el[s] + er[d];
  ev = (ev > 0.f ? ev : 0.f) + 1.0f;
  int2 pv; pv.x = s; pv.y = __float_as_int(ev);
  sed[pos] = pv;
}

// ---------------- K6: fused single-pass softmax + aggregation (unroll 8) ----
__global__ __launch_bounds__(256) void aggregate(const int* __restrict__ off,
                         const int* __restrict__ bscan,
                         const int2* __restrict__ sed,
                         const unsigned short* __restrict__ ftb,
                         float* __restrict__ out) {
  int node = (int)((blockIdx.x * blockDim.x + threadIdx.x) >> 6);
  int lane = threadIdx.x & 63;
  if (node >= N_NODES) return;
  int start = off[node] + bscan[node >> 10];
  int end = (node == N_NODES - 1) ? N_EDGES
                                  : off[node + 1] + bscan[(node + 1) >> 10];

  f32x4 a0 = (f32x4)0.f, a1 = (f32x4)0.f, a2 = (f32x4)0.f, a3 = (f32x4)0.f;
  float d0 = 0.f, d1 = 0.f, d2 = 0.f, d3 = 0.f;

#define EDGE(acc, den, sidx, sval)                                   \
  {                                                                  \
    uint2 v = *((const uint2*)(ftb + (size_t)(sidx) * OUT_DIM) + lane); \
    float w = __expf(__int_as_float(sval));                          \
    den += w;                                                        \
    acc[0] += w * bf2f((unsigned short)(v.x & 0xFFFF));              \
    acc[1] += w * bf2f((unsigned short)(v.x >> 16));                 \
    acc[2] += w * bf2f((unsigned short)(v.y & 0xFFFF));              \
    acc[3] += w * bf2f((unsigned short)(v.y >> 16));                 \
  }

  int i = start;
  for (; i + 8 <= end; i += 8) {
    int4 s01 = *(const int4*)(sed + i);
    int4 s23 = *(const int4*)(sed + i + 2);
    int4 s45 = *(const int4*)(sed + i + 4);
    int4 s67 = *(const int4*)(sed + i + 6);
    EDGE(a0, d0, s01.x, s01.y) EDGE(a1, d1, s01.z, s01.w)
    EDGE(a2, d2, s23.x, s23.y) EDGE(a3, d3, s23.z, s23.w)
    EDGE(a0, d0, s45.x, s45.y) EDGE(a1, d1, s45.z, s45.w)
    EDGE(a2, d2, s67.x, s67.y) EDGE(a3, d3, s67.z, s67.w)
  }
  for (; i + 2 <= end; i += 2) {
    int4 s01 = *(const int4*)(sed + i);
    EDGE(a0, d0, s01.x, s01.y) EDGE(a1, d1, s01.z, s01.w)
  }
  for (; i < end; ++i) {
    int2 e0 = sed[i];
    EDGE(a0, d0, e0.x, e0.y)
  }
#undef EDGE

  f32x4 acc = (a0 + a1) + (a2 + a3);
  float dsum = (d0 + d1) + (d2 + d3);
  float inv = (end > start) ? 1.0f / dsum : 0.f;
  acc *= inv;
  __builtin_nontemporal_store(acc, (f32x4*)(out + (size_t)node * OUT_DIM + lane * 4));
}

// ---------------- launch ----------------------------------------------------
extern "C" void kernel_launch(void* const* d_in, const int* in_sizes, int n_in,
                              void* d_out, int out_size, void* d_ws, size_t ws_size,
                              hipStream_t stream) {
  const float* feat = (const float*)d_in[0];
  // d_in[1] = p (unused in eval path)
  const float* Wl = (const float*)d_in[2];
  const float* bl = (const float*)d_in[3];
  const float* Wr = (const float*)d_in[4];
  const float* br = (const float*)d_in[5];
  const float* W  = (const float*)d_in[6];
  const float* b  = (const float*)d_in[7];
  const int* src  = (const int*)d_in[8];
  const int* dst  = (const int*)d_in[9];
  float* out = (float*)d_out;

  char* ws = (char*)d_ws;
  float* el = (float*)ws;            ws += (size_t)N_NODES * 4;
  float* er = (float*)ws;            ws += (size_t)N_NODES * 4;
  unsigned short* Wtp = (unsigned short*)ws;  ws += (size_t)OUT_DIM * IN_DIM * 2;
  unsigned short* ftb = (unsigned short*)ws;  ws += (size_t)N_NODES * OUT_DIM * 2;
  int* deg  = (int*)ws;              ws += (size_t)N_NODES * 4;
  int* cnt  = (int*)ws;              ws += (size_t)N_NODES * 4;
  int* off  = (int*)ws;              ws += (size_t)(N_NODES + 1) * 4;
  int2* sed = (int2*)ws;             ws += (size_t)N_EDGES * 8;
  int* bsum = (int*)ws;              ws += 64 * 4;
  int* bscan = (int*)ws;             ws += 64 * 4;

  hipMemsetAsync(deg, 0, (size_t)N_NODES * 4 * 2, stream);   // deg + cnt

  wconv_deg<<<WCONV_BLKS + (N_EDGES + 255) / 256, 256, 0, stream>>>(W, Wtp, dst, deg);
  gemm_mfma<<<(N_NODES + BROWS - 1) / BROWS, 512, 0, stream>>>(feat, Wtp, b,
                                                    Wl, bl, Wr, br, ftb, el, er);
  scan_local<<<NBLK_SCAN, 1024, 0, stream>>>(deg, off, bsum);
  scan_bsums<<<1, 64, 0, stream>>>(bsum, bscan);
  scatter_edges<<<(N_EDGES + 255) / 256, 256, 0, stream>>>(src, dst, el, er, off,
                                                           bscan, cnt, sed);
  aggregate<<<(N_NODES + 3) / 4, 256, 0, stream>>>(off, bscan, sed, ftb, out);
}

// Round 15
// 192.314 us; speedup vs baseline: 1.0138x; 1.0138x over previous
//
#include <hip/hip_runtime.h>
#include <math.h>
#include <stdint.h>

#define N_NODES 50000
#define N_EDGES 800000
#define IN_DIM  512
#define OUT_DIM 256
#define NBLK_SCAN 49   // ceil(50000/1024)
#define NGEMM 1563     // ceil(50000/32)

typedef __attribute__((ext_vector_type(8))) short short8;
typedef __attribute__((ext_vector_type(4))) float f32x4;

__device__ inline unsigned f2bf(float x) {
  unsigned u = __float_as_uint(x);
  return (u + 0x7FFFu + ((u >> 16) & 1u)) >> 16;   // RNE
}
__device__ inline float bf2f(unsigned short h) {
  return __uint_as_float(((unsigned)h) << 16);
}

// ---------------- K1: fused wconv (blocks 0..511) + deg_count (rest) --------
// Wtp[((nt*16+kk)*64 + lane)*8 + j] = bf16(W[k][c]), k=kk*32+(lane>>4)*8+j,
// c = nt*16 + (lane&15).
#define WCONV_BLKS 512
__global__ __launch_bounds__(256) void wconv_deg(const float* __restrict__ W,
                                                 unsigned short* __restrict__ Wtp,
                                                 const int* __restrict__ dst,
                                                 int* __restrict__ deg) {
  if (blockIdx.x < WCONV_BLKS) {
    int i = blockIdx.x * 256 + threadIdx.x;   // over 131072
    int c = i & 255, k = i >> 8;
    int nt = c >> 4, kk = k >> 5;
    int lane = (((k & 31) >> 3) << 4) | (c & 15);
    int j = k & 7;
    Wtp[(((size_t)(nt * 16 + kk)) * 64 + lane) * 8 + j] =
        (unsigned short)f2bf(W[(size_t)k * OUT_DIM + c]);
  } else {
    int e = (blockIdx.x - WCONV_BLKS) * 256 + threadIdx.x;
    if (e < N_EDGES) atomicAdd(&deg[dst[e]], 1);
  }
}

// ---------------- K2: gemm (blocks < NGEMM) + scan (last 49 blocks) ---------
// gemm: round-13 structure (proven 61us): 512 thr = 8 waves, 32 rows x 256
// cols, full K, feat->LDS frag-major, W streamed from L2 with dist-1 prefetch.
// scan: 2-level exclusive scan of deg with last-finisher bsum scan (device-
// scope atomics -> deterministic bscan).
#define GBM 32
__global__ __launch_bounds__(512) void gemm_scan(const float* __restrict__ feat,
                        const unsigned short* __restrict__ Wtp,
                        const float* __restrict__ bias,
                        const float* __restrict__ Wl, const float* __restrict__ bl,
                        const float* __restrict__ Wr, const float* __restrict__ br,
                        unsigned short* __restrict__ ftb,
                        float* __restrict__ el, float* __restrict__ er,
                        const int* __restrict__ deg, int* __restrict__ off,
                        int* __restrict__ bsum, int* __restrict__ bscan,
                        int* __restrict__ done) {
  __shared__ unsigned short Bs[16384];        // 32 KB (scan reuses as int buf)

  if (blockIdx.x >= NGEMM) {
    // ================= scan part =================
    int* ibuf = (int*)Bs;                     // [0..7] wave sums, [8] isLast
    int b = blockIdx.x - NGEMM;
    int t = threadIdx.x;
    int lane = t & 63, wid = t >> 6;
    int i0 = b * 1024 + 2 * t;
    int d0 = (i0 < N_NODES) ? deg[i0] : 0;
    int d1 = (i0 + 1 < N_NODES) ? deg[i0 + 1] : 0;
    int p = d0 + d1;
    int v = p;
    #pragma unroll
    for (int d = 1; d < 64; d <<= 1) {
      int x = __shfl_up(v, d);
      if (lane >= d) v += x;
    }
    if (lane == 63) ibuf[wid] = v;
    __syncthreads();
    if (wid == 0 && lane < 8) {
      int wv = ibuf[lane];
      int wo = wv;
      #pragma unroll
      for (int d = 1; d < 8; d <<= 1) {
        int x = __shfl_up(wv, d);
        if (lane >= d) wv += x;
      }
      ibuf[lane] = wv - wo;                   // exclusive wave offsets
    }
    __syncthreads();
    int excl = (v - p) + ibuf[wid];
    if (i0 < N_NODES) off[i0] = excl;
    if (i0 + 1 < N_NODES) off[i0 + 1] = excl + d0;
    if (t == 511) {
      atomicExch(&bsum[b], excl + p);         // block total, device-coherent
      __threadfence();
      int old = atomicAdd(done, 1);
      ibuf[8] = (old == NBLK_SCAN - 1);
    }
    __syncthreads();
    if (ibuf[8] && wid == 0) {                // last finisher scans bsums
      int bv = (lane < NBLK_SCAN) ? atomicAdd(&bsum[lane], 0) : 0;
      int orig = bv;
      #pragma unroll
      for (int d = 1; d < 64; d <<= 1) {
        int x = __shfl_up(bv, d);
        if (lane >= d) bv += x;
      }
      if (lane < NBLK_SCAN) bscan[lane] = bv - orig;   // exclusive
    }
    return;
  }

  // ================= gemm part (round-13 body) =================
  const int tid  = threadIdx.x;
  const int lane = tid & 63;
  const int wv   = tid >> 6;          // 0..7
  const int m0   = blockIdx.x * GBM;

  const int l15   = lane & 15;
  const int r     = wv * 4 + (lane >> 4);     // row within tile, 0..31
  const int row16 = r & 15;
  const int mg    = r >> 4;
  const int kgrp  = (l15 >> 1) & 3;
  const int b3    = l15 >> 3;
  const int h     = lane & 1;
  int grow = m0 + r;
  int gc   = grow < N_NODES ? grow : N_NODES - 1;
  const float4* frow = (const float4*)(feat + (size_t)gc * IN_DIM);
  const float4* wl4  = (const float4*)Wl;
  const float4* wr4  = (const float4*)Wr;

  float elp = 0.f, erp = 0.f;
  #pragma unroll
  for (int half = 0; half < 2; ++half) {
    float4 f[4], wlv[4], wrv[4];
    #pragma unroll
    for (int q = 0; q < 4; ++q) {
      int c4 = l15 + 16 * (half * 4 + q);
      f[q]   = frow[c4];
      wlv[q] = wl4[c4];
      wrv[q] = wr4[c4];
    }
    #pragma unroll
    for (int q = 0; q < 4; ++q) {
      int j = half * 4 + q;
      elp += f[q].x * wlv[q].x + f[q].y * wlv[q].y + f[q].z * wlv[q].z + f[q].w * wlv[q].w;
      erp += f[q].x * wrv[q].x + f[q].y * wrv[q].y + f[q].z * wrv[q].z + f[q].w * wrv[q].w;
      uint2 pv;
      pv.x = f2bf(f[q].x) | (f2bf(f[q].y) << 16);
      pv.y = f2bf(f[q].z) | (f2bf(f[q].w) << 16);
      int kk   = 2 * j + b3;
      int slot = (kgrp * 16 + row16) ^ (kk & 7) ^ ((row16 & 3) << 1);
      *(uint2*)((char*)Bs + (((mg * 16 + kk) * 64) + slot) * 16 + h * 8) = pv;
    }
  }
  #pragma unroll
  for (int o = 1; o < 16; o <<= 1) {
    elp += __shfl_xor(elp, o);
    erp += __shfl_xor(erp, o);
  }
  if (l15 == 0 && grow < N_NODES) {
    el[grow] = elp + bl[0];
    er[grow] = erp + br[0];
  }
  __syncthreads();

  // compute: LDS feat + L2 W-frags (distance-1 prefetch) + MFMA
  f32x4 acc[2][2];
  acc[0][0] = (f32x4)0.f; acc[0][1] = (f32x4)0.f;
  acc[1][0] = (f32x4)0.f; acc[1][1] = (f32x4)0.f;
  const int nt0 = wv * 2;
  const unsigned short* wp0 = Wtp + (((size_t)(nt0 + 0) * 16) * 64 + lane) * 8;
  const unsigned short* wp1 = Wtp + (((size_t)(nt0 + 1) * 16) * 64 + lane) * 8;
  const int rlane = lane & 15;
  short8 w0 = *(const short8*)wp0;
  short8 w1 = *(const short8*)wp1;
  #pragma unroll
  for (int kk = 0; kk < 16; ++kk) {
    short8 nw0, nw1;
    if (kk < 15) {
      nw0 = *(const short8*)(wp0 + (size_t)(kk + 1) * 512);
      nw1 = *(const short8*)(wp1 + (size_t)(kk + 1) * 512);
    }
    int slotr = lane ^ (kk & 7) ^ ((rlane & 3) << 1);
    short8 fa0 = *(const short8*)((char*)Bs + (((0 * 16 + kk) * 64) + slotr) * 16);
    short8 fa1 = *(const short8*)((char*)Bs + (((1 * 16 + kk) * 64) + slotr) * 16);
    acc[0][0] = __builtin_amdgcn_mfma_f32_16x16x32_bf16(w0, fa0, acc[0][0], 0, 0, 0);
    acc[0][1] = __builtin_amdgcn_mfma_f32_16x16x32_bf16(w1, fa0, acc[0][1], 0, 0, 0);
    acc[1][0] = __builtin_amdgcn_mfma_f32_16x16x32_bf16(w0, fa1, acc[1][0], 0, 0, 0);
    acc[1][1] = __builtin_amdgcn_mfma_f32_16x16x32_bf16(w1, fa1, acc[1][1], 0, 0, 0);
    w0 = nw0; w1 = nw1;
  }

  #pragma unroll
  for (int mgi = 0; mgi < 2; ++mgi) {
    int row = m0 + mgi * 16 + l15;
    if (row < N_NODES) {
      unsigned short* orow = ftb + (size_t)row * OUT_DIM;
      #pragma unroll
      for (int t = 0; t < 2; ++t) {
        int col = (nt0 + t) * 16 + (lane >> 4) * 4;
        float4 bb = *(const float4*)(bias + col);
        f32x4 vv = acc[mgi][t];
        uint2 pv;
        pv.x = f2bf(vv[0] + bb.x) | (f2bf(vv[1] + bb.y) << 16);
        pv.y = f2bf(vv[2] + bb.z) | (f2bf(vv[3] + bb.w) << 16);
        *(uint2*)(orow + col) = pv;
      }
    }
  }
}

// ---------------- K3: scatter edges into CSR, 2 edges/thread ----------------
__global__ void scatter_edges(const int* __restrict__ src, const int* __restrict__ dst,
                              const float* __restrict__ el, const float* __restrict__ er,
                              const int* __restrict__ off, const int* __restrict__ bscan,
                              int* __restrict__ cnt, int2* __restrict__ sed) {
  int g = blockIdx.x * blockDim.x + threadIdx.x;
  int e = g * 2;
  if (e >= N_EDGES) return;
  int2 s2 = *(const int2*)(src + e);
  int2 d2 = *(const int2*)(dst + e);
  float el0 = el[s2.x], er0 = er[d2.x];
  float el1 = el[s2.y], er1 = er[d2.y];
  float ev0 = el0 + er0; ev0 = (ev0 > 0.f ? ev0 : 0.f) + 1.0f;
  float ev1 = el1 + er1; ev1 = (ev1 > 0.f ? ev1 : 0.f) + 1.0f;
  int base0 = off[d2.x] + bscan[d2.x >> 10];
  int base1 = off[d2.y] + bscan[d2.y >> 10];
  int pos0 = base0 + atomicAdd(&cnt[d2.x], 1);
  int pos1 = base1 + atomicAdd(&cnt[d2.y], 1);
  int2 pv0; pv0.x = s2.x; pv0.y = __float_as_int(ev0);
  int2 pv1; pv1.x = s2.y; pv1.y = __float_as_int(ev1);
  sed[pos0] = pv0;
  sed[pos1] = pv1;
}

// ---------------- K4: fused single-pass softmax + aggregation (unroll 8) ----
__global__ __launch_bounds__(256) void aggregate(const int* __restrict__ off,
                         const int* __restrict__ bscan,
                         const int2* __restrict__ sed,
                         const unsigned short* __restrict__ ftb,
                         float* __restrict__ out) {
  int node = (int)((blockIdx.x * blockDim.x + threadIdx.x) >> 6);
  int lane = threadIdx.x & 63;
  if (node >= N_NODES) return;
  int start = off[node] + bscan[node >> 10];
  int end = (node == N_NODES - 1) ? N_EDGES
                                  : off[node + 1] + bscan[(node + 1) >> 10];

  f32x4 a0 = (f32x4)0.f, a1 = (f32x4)0.f, a2 = (f32x4)0.f, a3 = (f32x4)0.f;
  float d0 = 0.f, d1 = 0.f, d2 = 0.f, d3 = 0.f;

#define EDGE(acc, den, sidx, sval)                                   \
  {                                                                  \
    uint2 v = *((const uint2*)(ftb + (size_t)(sidx) * OUT_DIM) + lane); \
    float w = __expf(__int_as_float(sval));                          \
    den += w;                                                        \
    acc[0] += w * bf2f((unsigned short)(v.x & 0xFFFF));              \
    acc[1] += w * bf2f((unsigned short)(v.x >> 16));                 \
    acc[2] += w * bf2f((unsigned short)(v.y & 0xFFFF));              \
    acc[3] += w * bf2f((unsigned short)(v.y >> 16));                 \
  }

  int i = start;
  for (; i + 8 <= end; i += 8) {
    int4 s01 = *(const int4*)(sed + i);
    int4 s23 = *(const int4*)(sed + i + 2);
    int4 s45 = *(const int4*)(sed + i + 4);
    int4 s67 = *(const int4*)(sed + i + 6);
    EDGE(a0, d0, s01.x, s01.y) EDGE(a1, d1, s01.z, s01.w)
    EDGE(a2, d2, s23.x, s23.y) EDGE(a3, d3, s23.z, s23.w)
    EDGE(a0, d0, s45.x, s45.y) EDGE(a1, d1, s45.z, s45.w)
    EDGE(a2, d2, s67.x, s67.y) EDGE(a3, d3, s67.z, s67.w)
  }
  for (; i + 2 <= end; i += 2) {
    int4 s01 = *(const int4*)(sed + i);
    EDGE(a0, d0, s01.x, s01.y) EDGE(a1, d1, s01.z, s01.w)
  }
  for (; i < end; ++i) {
    int2 e0 = sed[i];
    EDGE(a0, d0, e0.x, e0.y)
  }
#undef EDGE

  f32x4 acc = (a0 + a1) + (a2 + a3);
  float dsum = (d0 + d1) + (d2 + d3);
  float inv = (end > start) ? 1.0f / dsum : 0.f;
  acc *= inv;
  __builtin_nontemporal_store(acc, (f32x4*)(out + (size_t)node * OUT_DIM + lane * 4));
}

// ---------------- launch ----------------------------------------------------
extern "C" void kernel_launch(void* const* d_in, const int* in_sizes, int n_in,
                              void* d_out, int out_size, void* d_ws, size_t ws_size,
                              hipStream_t stream) {
  const float* feat = (const float*)d_in[0];
  // d_in[1] = p (unused in eval path)
  const float* Wl = (const float*)d_in[2];
  const float* bl = (const float*)d_in[3];
  const float* Wr = (const float*)d_in[4];
  const float* br = (const float*)d_in[5];
  const float* W  = (const float*)d_in[6];
  const float* b  = (const float*)d_in[7];
  const int* src  = (const int*)d_in[8];
  const int* dst  = (const int*)d_in[9];
  float* out = (float*)d_out;

  char* ws = (char*)d_ws;
  float* el = (float*)ws;            ws += (size_t)N_NODES * 4;
  float* er = (float*)ws;            ws += (size_t)N_NODES * 4;
  unsigned short* Wtp = (unsigned short*)ws;  ws += (size_t)OUT_DIM * IN_DIM * 2;
  unsigned short* ftb = (unsigned short*)ws;  ws += (size_t)N_NODES * OUT_DIM * 2;
  int* deg  = (int*)ws;              ws += (size_t)N_NODES * 4;
  int* cnt  = (int*)ws;              ws += (size_t)N_NODES * 4;
  int* done = (int*)ws;              ws += 16 * 4;
  int* off  = (int*)ws;              ws += (size_t)(N_NODES + 1) * 4;
  int2* sed = (int2*)ws;             ws += (size_t)N_EDGES * 8;
  int* bsum = (int*)ws;              ws += 64 * 4;
  int* bscan = (int*)ws;             ws += 64 * 4;

  // zero deg + cnt + done (contiguous)
  hipMemsetAsync(deg, 0, ((size_t)N_NODES * 2 + 16) * 4, stream);

  wconv_deg<<<WCONV_BLKS + (N_EDGES + 255) / 256, 256, 0, stream>>>(W, Wtp, dst, deg);
  gemm_scan<<<NGEMM + NBLK_SCAN, 512, 0, stream>>>(feat, Wtp, b, Wl, bl, Wr, br,
                                                   ftb, el, er, deg, off, bsum,
                                                   bscan, done);
  scatter_edges<<<(N_EDGES / 2 + 255) / 256, 256, 0, stream>>>(src, dst, el, er, off,
                                                               bscan, cnt, sed);
  aggregate<<<(N_NODES + 3) / 4, 256, 0, stream>>>(off, bscan, sed, ftb, out);
}